// Round 4
// baseline (2223.984 us; speedup 1.0000x reference)
//
#include <hip/hip_runtime.h>
#include <hip/hip_bf16.h>

// Problem constants
#define BB     2
#define SEQ    256
#define HH     2048
#define HKc    16
#define HVc    32
#define DKc    128
#define DVc    128
#define KC     4
#define KEYD   2048      // HKc*DKc
#define VALD   4096      // HVc*DVc
#define CONVD  8192      // 2*KEYD + VALD
#define MM     (BB*SEQ)  // 512
#define EPSf   1e-6f

// ---------------- fp32 tiled GEMM: C[M,N] = A[M,K] * B[K,N] ----------------
__global__ __launch_bounds__(256) void gemm_f32(
    const float* __restrict__ A, const float* __restrict__ Bw,
    float* __restrict__ C, int M, int N, int Kd) {
  constexpr int BM = 64, BN = 64, BK = 16;
  __shared__ float As[BK][BM + 4];
  __shared__ float Bs[BK][BN + 4];
  const int tid = threadIdx.x;
  const int tx = tid & 15, ty = tid >> 4;
  const int bn = blockIdx.x * BN, bm = blockIdx.y * BM;
  const int la_c = tid & 15;   // k-col within A tile
  const int la_r = tid >> 4;   // row base (+16 x4)
  const int lb_n = tid & 63;   // n within B tile
  const int lb_k = tid >> 6;   // k base (+4 x4)
  float acc[4][4] = {};
  for (int k0 = 0; k0 < Kd; k0 += BK) {
#pragma unroll
    for (int r = la_r; r < BM; r += 16) {
      int gr = bm + r;
      As[la_c][r] = (gr < M) ? A[(size_t)gr * Kd + k0 + la_c] : 0.f;
    }
#pragma unroll
    for (int kk = lb_k; kk < BK; kk += 4) {
      int gc = bn + lb_n;
      Bs[kk][lb_n] = (gc < N) ? Bw[(size_t)(k0 + kk) * N + gc] : 0.f;
    }
    __syncthreads();
#pragma unroll
    for (int k = 0; k < BK; ++k) {
      float4 a4 = *(const float4*)&As[k][ty * 4];
      float4 b4 = *(const float4*)&Bs[k][tx * 4];
      float av[4] = {a4.x, a4.y, a4.z, a4.w};
      float bv[4] = {b4.x, b4.y, b4.z, b4.w};
#pragma unroll
      for (int i = 0; i < 4; ++i)
#pragma unroll
        for (int j = 0; j < 4; ++j) acc[i][j] += av[i] * bv[j];
    }
    __syncthreads();
  }
#pragma unroll
  for (int i = 0; i < 4; ++i) {
    int gr = bm + ty * 4 + i;
    if (gr >= M) continue;
    int gc = bn + tx * 4;
    *(float4*)&C[(size_t)gr * N + gc] =
        make_float4(acc[i][0], acc[i][1], acc[i][2], acc[i][3]);
  }
}

// Final GEMM: A fp32 strided (lda), C fp32
__global__ __launch_bounds__(256) void gemm_out(
    const float* __restrict__ A, const float* __restrict__ Bw,
    float* __restrict__ C, int M, int N, int Kd, int lda) {
  constexpr int BM = 64, BN = 64, BK = 16;
  __shared__ float As[BK][BM + 4];
  __shared__ float Bs[BK][BN + 4];
  const int tid = threadIdx.x;
  const int tx = tid & 15, ty = tid >> 4;
  const int bn = blockIdx.x * BN, bm = blockIdx.y * BM;
  const int la_c = tid & 15;
  const int la_r = tid >> 4;
  const int lb_n = tid & 63;
  const int lb_k = tid >> 6;
  float acc[4][4] = {};
  for (int k0 = 0; k0 < Kd; k0 += BK) {
#pragma unroll
    for (int r = la_r; r < BM; r += 16) {
      int gr = bm + r;
      As[la_c][r] = (gr < M) ? A[(size_t)gr * lda + k0 + la_c] : 0.f;
    }
#pragma unroll
    for (int kk = lb_k; kk < BK; kk += 4) {
      int gc = bn + lb_n;
      Bs[kk][lb_n] = (gc < N) ? Bw[(size_t)(k0 + kk) * N + gc] : 0.f;
    }
    __syncthreads();
#pragma unroll
    for (int k = 0; k < BK; ++k) {
      float4 a4 = *(const float4*)&As[k][ty * 4];
      float4 b4 = *(const float4*)&Bs[k][tx * 4];
      float av[4] = {a4.x, a4.y, a4.z, a4.w};
      float bv[4] = {b4.x, b4.y, b4.z, b4.w};
#pragma unroll
      for (int i = 0; i < 4; ++i)
#pragma unroll
        for (int j = 0; j < 4; ++j) acc[i][j] += av[i] * bv[j];
    }
    __syncthreads();
  }
#pragma unroll
  for (int i = 0; i < 4; ++i) {
    int gr = bm + ty * 4 + i;
    if (gr >= M) continue;
    int gc = bn + tx * 4;
    *(float4*)&C[(size_t)gr * N + gc] =
        make_float4(acc[i][0], acc[i][1], acc[i][2], acc[i][3]);
  }
}

// -------- b/a projections fused with gating --------
__global__ __launch_bounds__(256) void proj_ab_kernel(
    const float* __restrict__ hs, const float* __restrict__ Wb,
    const float* __restrict__ Wa, const float* __restrict__ A_log,
    const float* __restrict__ dt_bias, float* __restrict__ g_out,
    float* __restrict__ beta_out) {
  __shared__ float xs[HH];
  __shared__ float part[4][64];
  const int row = blockIdx.x;
  const int t = threadIdx.x;
  for (int i = t; i < HH; i += 256) xs[i] = hs[(size_t)row * HH + i];
  __syncthreads();
  const int j = t & 63;
  const int kc = t >> 6;
  const float* W = (j < 32) ? Wb : Wa;
  const int jj = j & 31;
  float p = 0.f;
  const int k0 = kc * 512;
#pragma unroll 8
  for (int k = k0; k < k0 + 512; ++k) p += xs[k] * W[k * 32 + jj];
  part[kc][j] = p;
  __syncthreads();
  if (t < 64) {
    float dot = part[0][t] + part[1][t] + part[2][t] + part[3][t];
    if (t < 32) {
      beta_out[row * HVc + t] = 1.f / (1.f + expf(-dot));
    } else {
      int h = t - 32;
      float x = dot + dt_bias[h];
      float sp = (x > 20.f) ? x : log1pf(expf(x));
      g_out[row * HVc + h] = -expf(A_log[h]) * sp;
    }
  }
}

// -------- depthwise causal conv (K=4) + SiLU, IN PLACE on mixed --------
// One thread per (b,c); streams s with a 3-register raw window.
// Emits conv_state_out (last K-1 raw inputs, [B,C,K-1], fp32).
__global__ __launch_bounds__(256) void conv_inplace_kernel(
    float* __restrict__ mixed, const float* __restrict__ conv_state,
    const float* __restrict__ conv_w, const float* __restrict__ conv_b,
    float* __restrict__ cs_out) {
  int idx = blockIdx.x * 256 + threadIdx.x;  // over BB*CONVD
  int c = idx & (CONVD - 1);
  int b = idx >> 13;
  const float w0 = conv_w[c * KC + 0], w1 = conv_w[c * KC + 1];
  const float w2 = conv_w[c * KC + 2], w3 = conv_w[c * KC + 3];
  const float bias = conv_b[c];
  size_t sb = (size_t)b * CONVD * (KC - 1) + (size_t)c * (KC - 1);
  float r0 = conv_state[sb + 0];   // raw[s-3]
  float r1 = conv_state[sb + 1];   // raw[s-2]
  float r2 = conv_state[sb + 2];   // raw[s-1]
  for (int s = 0; s < SEQ; ++s) {
    size_t off = ((size_t)(b * SEQ + s)) * CONVD + c;
    float x = mixed[off];
    float acc = bias + r0 * w0 + r1 * w1 + r2 * w2 + x * w3;
    float sig = 1.f / (1.f + expf(-acc));
    mixed[off] = acc * sig;
    r0 = r1; r1 = r2; r2 = x;
  }
  cs_out[sb + 0] = r0;
  cs_out[sb + 1] = r1;
  cs_out[sb + 2] = r2;
}

// -------- per-head l2norm of q (scaled by DK^-0.5) and k, IN PLACE --------
__global__ __launch_bounds__(64) void l2norm_kernel(float* __restrict__ mixed) {
  int bx = blockIdx.x;          // row*32 + head*2 + which
  int which = bx & 1;
  int head = (bx >> 1) & 15;
  int row = bx >> 5;
  int lane = threadIdx.x;
  size_t base = (size_t)row * CONVD + (size_t)which * KEYD + head * DKc;
  float v0 = mixed[base + lane];
  float v1 = mixed[base + lane + 64];
  float ss = v0 * v0 + v1 * v1;
#pragma unroll
  for (int m = 1; m < 64; m <<= 1) ss += __shfl_xor(ss, m, 64);
  float rn = rsqrtf(ss + EPSf);
  if (!which) rn *= 0.08838834764831845f;  // DK^-0.5
  mixed[base + lane] = v0 * rn;
  mixed[base + lane + 64] = v1 * rn;
}

// -------- delta-rule scan: one block per (b,h); o overwrites v slot --------
__global__ __launch_bounds__(256) void scan_kernel(
    float* __restrict__ mixed, const float* __restrict__ g_in,
    const float* __restrict__ beta_in, const float* __restrict__ rs0,
    const int* __restrict__ ctx, float* __restrict__ sfin) {
  const int bh = blockIdx.x;          // b*HV + h
  const int b = bh >> 5, h = bh & 31;
  const int t = threadIdx.x;
  const int khf = t & 1;              // which 64-wide k-half
  const int v = t >> 1;               // column 0..127
  const int khead = h >> 1;           // GQA: rep=2
  __shared__ float ksh[128], qsh[128];
  float Sreg[64];
#pragma unroll
  for (int i = 0; i < 64; ++i)
    Sreg[i] = rs0[((size_t)bh * DKc + khf * 64 + i) * DVc + v];
  const int cl = ctx[b];
  for (int s = 0; s < SEQ; ++s) {
    const int row = b * SEQ + s;
    const size_t rbase = (size_t)row * CONVD;
    if (t < 128) ksh[t] = mixed[rbase + KEYD + khead * DKc + t];
    else qsh[t - 128] = mixed[rbase + khead * DKc + (t - 128)];
    float vval = mixed[rbase + 2 * KEYD + h * DVc + v];
    float gg = g_in[row * HVc + h];
    float bt = beta_in[row * HVc + h];
    __syncthreads();                  // all reads of this row done
    if (s < cl) {
      float eg = expf(gg);
      const float4* k4 = (const float4*)&ksh[khf * 64];
      const float4* q4 = (const float4*)&qsh[khf * 64];
      float kvp = 0.f;
#pragma unroll
      for (int i = 0; i < 16; ++i) {
        float4 kk = k4[i];
        Sreg[4 * i + 0] *= eg; kvp += kk.x * Sreg[4 * i + 0];
        Sreg[4 * i + 1] *= eg; kvp += kk.y * Sreg[4 * i + 1];
        Sreg[4 * i + 2] *= eg; kvp += kk.z * Sreg[4 * i + 2];
        Sreg[4 * i + 3] *= eg; kvp += kk.w * Sreg[4 * i + 3];
      }
      float kv = kvp + __shfl_xor(kvp, 1, 64);
      float delta = (vval - kv) * bt;
      float op = 0.f;
#pragma unroll
      for (int i = 0; i < 16; ++i) {
        float4 kk = k4[i];
        float4 qq = q4[i];
        Sreg[4 * i + 0] += kk.x * delta; op += qq.x * Sreg[4 * i + 0];
        Sreg[4 * i + 1] += kk.y * delta; op += qq.y * Sreg[4 * i + 1];
        Sreg[4 * i + 2] += kk.z * delta; op += qq.z * Sreg[4 * i + 2];
        Sreg[4 * i + 3] += kk.w * delta; op += qq.w * Sreg[4 * i + 3];
      }
      float o = op + __shfl_xor(op, 1, 64);
      if (!khf) mixed[rbase + 2 * KEYD + h * DVc + v] = o;  // in-place o
    } else {
      if (!khf) mixed[rbase + 2 * KEYD + h * DVc + v] = 0.f;
    }
    __syncthreads();
  }
#pragma unroll
  for (int i = 0; i < 64; ++i)
    sfin[((size_t)bh * DKc + khf * 64 + i) * DVc + v] = Sreg[i];
}

// -------- gated RMSNorm over DV + SiLU(z), in place on o (v-slot of mixed) ----
__global__ __launch_bounds__(64) void normgate_kernel(
    float* __restrict__ mixed, const float* __restrict__ zbuf,
    const float* __restrict__ norm_w) {
  int bx = blockIdx.x;   // row*32 + h
  int h = bx & 31;
  int row = bx >> 5;
  int lane = threadIdx.x;
  size_t base = (size_t)row * CONVD + 2 * KEYD + h * DVc;
  size_t zb = (size_t)row * VALD + h * DVc;
  float o0 = mixed[base + lane];
  float o1 = mixed[base + lane + 64];
  float ss = o0 * o0 + o1 * o1;
#pragma unroll
  for (int m = 1; m < 64; m <<= 1) ss += __shfl_xor(ss, m, 64);
  float rms = rsqrtf(ss * (1.f / 128.f) + EPSf);
  float z0 = zbuf[zb + lane];
  float z1 = zbuf[zb + lane + 64];
  mixed[base + lane]      = o0 * rms * norm_w[lane]      * (z0 / (1.f + expf(-z0)));
  mixed[base + lane + 64] = o1 * rms * norm_w[lane + 64] * (z1 / (1.f + expf(-z1)));
}

extern "C" void kernel_launch(void* const* d_in, const int* in_sizes, int n_in,
                              void* d_out, int out_size, void* d_ws, size_t ws_size,
                              hipStream_t stream) {
  const float* hs        = (const float*)d_in[0];
  const float* conv_st   = (const float*)d_in[1];
  const float* rec_st    = (const float*)d_in[2];
  const int*   ctx       = (const int*)d_in[3];
  const float* W_qkv     = (const float*)d_in[4];
  const float* W_z       = (const float*)d_in[5];
  const float* W_b       = (const float*)d_in[6];
  const float* W_a       = (const float*)d_in[7];
  const float* conv_w    = (const float*)d_in[8];
  const float* conv_b    = (const float*)d_in[9];
  const float* A_log     = (const float*)d_in[10];
  const float* dt_bias   = (const float*)d_in[11];
  const float* norm_w    = (const float*)d_in[12];
  const float* W_out     = (const float*)d_in[13];

  // Outputs are fp32 (reference output dtype), concatenated in return order.
  float* out0   = (float*)d_out;                          // [B,S,H]
  float* out_cv = out0 + (size_t)MM * HH;                 // [B,CONVD,K-1]
  float* out_sf = out_cv + (size_t)BB * CONVD * (KC - 1); // [B,HV,DK,DV]

  float* mixed = (float*)d_ws;                        // MM*CONVD   (16 MB)
  float* zbuf  = mixed + (size_t)MM * CONVD;          // MM*VALD    (8 MB)
  float* gbuf  = zbuf + (size_t)MM * VALD;            // MM*HV
  float* betab = gbuf + (size_t)MM * HVc;             // MM*HV

  // 1) mixed = hs @ W_qkv
  gemm_f32<<<dim3(CONVD / 64, MM / 64), 256, 0, stream>>>(hs, W_qkv, mixed, MM, CONVD, HH);
  // 2) z = hs @ W_z
  gemm_f32<<<dim3(VALD / 64, MM / 64), 256, 0, stream>>>(hs, W_z, zbuf, MM, VALD, HH);
  // 3) b,a projections + gating
  proj_ab_kernel<<<MM, 256, 0, stream>>>(hs, W_b, W_a, A_log, dt_bias, gbuf, betab);
  // 4) conv + silu in place (+ conv_state_out fp32)
  conv_inplace_kernel<<<(BB * CONVD) / 256, 256, 0, stream>>>(mixed, conv_st, conv_w, conv_b, out_cv);
  // 5) l2norm q,k in place
  l2norm_kernel<<<MM * HKc * 2, 64, 0, stream>>>(mixed);
  // 6) delta-rule scan (o overwrites v slot; Sfin fp32 out)
  scan_kernel<<<BB * HVc, 256, 0, stream>>>(mixed, gbuf, betab, rec_st, ctx, out_sf);
  // 7) gated RMSNorm + silu(z) in place
  normgate_kernel<<<MM * HVc, 64, 0, stream>>>(mixed, zbuf, norm_w);
  // 8) output = o @ W_out (fp32 out), A strided with lda=CONVD
  gemm_out<<<dim3(HH / 64, MM / 64), 256, 0, stream>>>(
      mixed + 2 * KEYD, W_out, out0, MM, HH, VALD, CONVD);
}

// Round 5
// 944.807 us; speedup vs baseline: 2.3539x; 2.3539x over previous
//
#include <hip/hip_runtime.h>
#include <hip/hip_bf16.h>

// Problem constants
#define BB     2
#define SEQ    256
#define HH     2048
#define HKc    16
#define HVc    32
#define DKc    128
#define DVc    128
#define KC     4
#define KEYD   2048      // HKc*DKc
#define VALD   4096      // HVc*DVc
#define CONVD  8192      // 2*KEYD + VALD
#define MM     (BB*SEQ)  // 512
#define EPSf   1e-6f

typedef __attribute__((ext_vector_type(8))) short short8;
typedef __attribute__((ext_vector_type(4))) short short4v;
typedef __attribute__((ext_vector_type(4))) float floatx4;

__device__ __forceinline__ short f2bf(float f) {
  union { float f; unsigned u; } v; v.f = f;
  unsigned r = v.u + 0x7fffu + ((v.u >> 16) & 1u);   // RNE
  return (short)(r >> 16);
}

// ---------- MFMA bf16 GEMM: C[M,N] = A[M,K](fp32,lda) * B[K,N](fp32) -------
// Block tile 64m x 128n, BK=32, 256 threads = 4 waves (2x2), wave = 32m x 64n.
#define PADs 40   // shorts per LDS row: 32 data + 8 pad (80 B, 16B-aligned)
__global__ __launch_bounds__(256) void gemm_mfma(
    const float* __restrict__ A, const float* __restrict__ Bw,
    float* __restrict__ C, int M, int N, int Kd, int lda) {
  __shared__ short As[64 * PADs];
  __shared__ short Bs[128 * PADs];
  const int tid = threadIdx.x;
  const int wave = tid >> 6, lane = tid & 63;
  const int wm = (wave >> 1) * 32, wn = (wave & 1) * 64;
  const int bm = blockIdx.y * 64, bn = blockIdx.x * 128;
  floatx4 acc[2][4] = {};
  // A staging: kq = float4-index (8 per row), rows m0, m0+32
  const int a_kq = tid & 7, a_m0 = tid >> 3;
  // B staging (transpose): n = tid&127, k-runs of 8
  const int b_n = tid & 127, b_kh = (tid >> 7) * 8;
  const int fm = lane & 15, fq = (lane >> 4) * 8;
  for (int k0 = 0; k0 < Kd; k0 += 32) {
#pragma unroll
    for (int r = 0; r < 2; ++r) {
      int m = a_m0 + r * 32;
      const float4 f = *(const float4*)(A + (size_t)(bm + m) * lda + k0 + a_kq * 4);
      short4v sv; sv[0] = f2bf(f.x); sv[1] = f2bf(f.y); sv[2] = f2bf(f.z); sv[3] = f2bf(f.w);
      *(short4v*)&As[m * PADs + a_kq * 4] = sv;
    }
#pragma unroll
    for (int r = 0; r < 2; ++r) {
      int kk = b_kh + r * 16;
      short8 s;
#pragma unroll
      for (int j = 0; j < 8; ++j)
        s[j] = f2bf(Bw[(size_t)(k0 + kk + j) * N + bn + b_n]);
      *(short8*)&Bs[b_n * PADs + kk] = s;
    }
    __syncthreads();
    short8 af[2], bfr[4];
#pragma unroll
    for (int i = 0; i < 2; ++i)
      af[i] = *(const short8*)&As[(wm + i * 16 + fm) * PADs + fq];
#pragma unroll
    for (int j = 0; j < 4; ++j)
      bfr[j] = *(const short8*)&Bs[(wn + j * 16 + fm) * PADs + fq];
#pragma unroll
    for (int i = 0; i < 2; ++i)
#pragma unroll
      for (int j = 0; j < 4; ++j)
        acc[i][j] = __builtin_amdgcn_mfma_f32_16x16x32_bf16(af[i], bfr[j], acc[i][j], 0, 0, 0);
    __syncthreads();
  }
  // C/D layout: col = lane&15, row = (lane>>4)*4 + reg
  const int cn = lane & 15, cr0 = (lane >> 4) * 4;
#pragma unroll
  for (int i = 0; i < 2; ++i)
#pragma unroll
    for (int j = 0; j < 4; ++j)
#pragma unroll
      for (int r = 0; r < 4; ++r)
        C[(size_t)(bm + wm + i * 16 + cr0 + r) * N + bn + wn + j * 16 + cn] = acc[i][j][r];
}

// -------- b/a projections fused with gating --------
__global__ __launch_bounds__(256) void proj_ab_kernel(
    const float* __restrict__ hs, const float* __restrict__ Wb,
    const float* __restrict__ Wa, const float* __restrict__ A_log,
    const float* __restrict__ dt_bias, float* __restrict__ g_out,
    float* __restrict__ beta_out) {
  __shared__ float xs[HH];
  __shared__ float part[4][64];
  const int row = blockIdx.x;
  const int t = threadIdx.x;
  for (int i = t; i < HH; i += 256) xs[i] = hs[(size_t)row * HH + i];
  __syncthreads();
  const int j = t & 63;
  const int kc = t >> 6;
  const float* W = (j < 32) ? Wb : Wa;
  const int jj = j & 31;
  float p = 0.f;
  const int k0 = kc * 512;
#pragma unroll 8
  for (int k = k0; k < k0 + 512; ++k) p += xs[k] * W[k * 32 + jj];
  part[kc][j] = p;
  __syncthreads();
  if (t < 64) {
    float dot = part[0][t] + part[1][t] + part[2][t] + part[3][t];
    if (t < 32) {
      beta_out[row * HVc + t] = 1.f / (1.f + expf(-dot));
    } else {
      int h = t - 32;
      float x = dot + dt_bias[h];
      float sp = (x > 20.f) ? x : log1pf(expf(x));
      g_out[row * HVc + h] = -expf(A_log[h]) * sp;
    }
  }
}

// -------- depthwise causal conv (K=4) + SiLU, parallel over s-chunks --------
// Reads raw mixed, writes cs (separate buffer). CHUNK=16.
#define CCH 16
__global__ __launch_bounds__(256) void conv_par_kernel(
    const float* __restrict__ mixed, const float* __restrict__ conv_state,
    const float* __restrict__ conv_w, const float* __restrict__ conv_b,
    float* __restrict__ cs) {
  const int c = blockIdx.x * 256 + threadIdx.x;   // channel
  const int s0 = blockIdx.y * CCH;
  const int b = blockIdx.z;
  const float4 w4 = *(const float4*)&conv_w[c * KC];
  const float bias = conv_b[c];
  float r0, r1, r2;
  if (s0 == 0) {
    size_t sb = (size_t)(b * CONVD + c) * (KC - 1);
    r0 = conv_state[sb + 0]; r1 = conv_state[sb + 1]; r2 = conv_state[sb + 2];
  } else {
    r0 = mixed[((size_t)(b * SEQ + s0 - 3)) * CONVD + c];
    r1 = mixed[((size_t)(b * SEQ + s0 - 2)) * CONVD + c];
    r2 = mixed[((size_t)(b * SEQ + s0 - 1)) * CONVD + c];
  }
#pragma unroll
  for (int s = s0; s < s0 + CCH; ++s) {
    size_t off = ((size_t)(b * SEQ + s)) * CONVD + c;
    float x = mixed[off];
    float acc = bias + r0 * w4.x + r1 * w4.y + r2 * w4.z + x * w4.w;
    cs[off] = acc / (1.f + expf(-acc));
    r0 = r1; r1 = r2; r2 = x;
  }
}

// -------- conv_state_out: last K-1 raw rows of mixed, [B,C,K-1] fp32 --------
__global__ __launch_bounds__(256) void conv_state_out_kernel(
    const float* __restrict__ mixed, float* __restrict__ out2) {
  int idx = blockIdx.x * 256 + threadIdx.x;  // over BB*CONVD*(KC-1)
  int t = idx % (KC - 1);
  int c = (idx / (KC - 1)) & (CONVD - 1);
  int b = idx / ((KC - 1) * CONVD);
  out2[idx] = mixed[((size_t)(b * SEQ + SEQ - (KC - 1) + t)) * CONVD + c];
}

// -------- per-head l2norm of q (scaled by DK^-0.5) and k, IN PLACE on cs ----
__global__ __launch_bounds__(64) void l2norm_kernel(float* __restrict__ cs) {
  int bx = blockIdx.x;          // row*32 + head*2 + which
  int which = bx & 1;
  int head = (bx >> 1) & 15;
  int row = bx >> 5;
  int lane = threadIdx.x;
  size_t base = (size_t)row * CONVD + (size_t)which * KEYD + head * DKc;
  float v0 = cs[base + lane];
  float v1 = cs[base + lane + 64];
  float ss = v0 * v0 + v1 * v1;
#pragma unroll
  for (int m = 1; m < 64; m <<= 1) ss += __shfl_xor(ss, m, 64);
  float rn = rsqrtf(ss + EPSf);
  if (!which) rn *= 0.08838834764831845f;  // DK^-0.5
  cs[base + lane] = v0 * rn;
  cs[base + lane + 64] = v1 * rn;
}

// -------- delta-rule scan: one block per (b,h); o overwrites v slot of cs ---
__global__ __launch_bounds__(256) void scan_kernel(
    float* __restrict__ cs, const float* __restrict__ g_in,
    const float* __restrict__ beta_in, const float* __restrict__ rs0,
    const int* __restrict__ ctx, float* __restrict__ sfin) {
  const int bh = blockIdx.x;          // b*HV + h
  const int b = bh >> 5, h = bh & 31;
  const int t = threadIdx.x;
  const int khf = t & 1;              // which 64-wide k-half
  const int v = t >> 1;               // column 0..127
  const int khead = h >> 1;           // GQA: rep=2
  __shared__ float ksh[128], qsh[128];
  float Sreg[64];
#pragma unroll
  for (int i = 0; i < 64; ++i)
    Sreg[i] = rs0[((size_t)bh * DKc + khf * 64 + i) * DVc + v];
  const int cl = ctx[b];
  for (int s = 0; s < SEQ; ++s) {
    const int row = b * SEQ + s;
    const size_t rbase = (size_t)row * CONVD;
    if (t < 128) ksh[t] = cs[rbase + KEYD + khead * DKc + t];
    else qsh[t - 128] = cs[rbase + khead * DKc + (t - 128)];
    float vval = cs[rbase + 2 * KEYD + h * DVc + v];
    float gg = g_in[row * HVc + h];
    float bt = beta_in[row * HVc + h];
    __syncthreads();                  // all reads of this row done
    if (s < cl) {
      float eg = expf(gg);
      const float4* k4 = (const float4*)&ksh[khf * 64];
      const float4* q4 = (const float4*)&qsh[khf * 64];
      float kvp = 0.f;
#pragma unroll
      for (int i = 0; i < 16; ++i) {
        float4 kk = k4[i];
        Sreg[4 * i + 0] *= eg; kvp += kk.x * Sreg[4 * i + 0];
        Sreg[4 * i + 1] *= eg; kvp += kk.y * Sreg[4 * i + 1];
        Sreg[4 * i + 2] *= eg; kvp += kk.z * Sreg[4 * i + 2];
        Sreg[4 * i + 3] *= eg; kvp += kk.w * Sreg[4 * i + 3];
      }
      float kv = kvp + __shfl_xor(kvp, 1, 64);
      float delta = (vval - kv) * bt;
      float op = 0.f;
#pragma unroll
      for (int i = 0; i < 16; ++i) {
        float4 kk = k4[i];
        float4 qq = q4[i];
        Sreg[4 * i + 0] += kk.x * delta; op += qq.x * Sreg[4 * i + 0];
        Sreg[4 * i + 1] += kk.y * delta; op += qq.y * Sreg[4 * i + 1];
        Sreg[4 * i + 2] += kk.z * delta; op += qq.z * Sreg[4 * i + 2];
        Sreg[4 * i + 3] += kk.w * delta; op += qq.w * Sreg[4 * i + 3];
      }
      float o = op + __shfl_xor(op, 1, 64);
      if (!khf) cs[rbase + 2 * KEYD + h * DVc + v] = o;  // in-place o
    } else {
      if (!khf) cs[rbase + 2 * KEYD + h * DVc + v] = 0.f;
    }
    __syncthreads();
  }
#pragma unroll
  for (int i = 0; i < 64; ++i)
    sfin[((size_t)bh * DKc + khf * 64 + i) * DVc + v] = Sreg[i];
}

// -------- gated RMSNorm over DV + SiLU(z), in place on o (v-slot of cs) -----
__global__ __launch_bounds__(64) void normgate_kernel(
    float* __restrict__ cs, const float* __restrict__ zbuf,
    const float* __restrict__ norm_w) {
  int bx = blockIdx.x;   // row*32 + h
  int h = bx & 31;
  int row = bx >> 5;
  int lane = threadIdx.x;
  size_t base = (size_t)row * CONVD + 2 * KEYD + h * DVc;
  size_t zb = (size_t)row * VALD + h * DVc;
  float o0 = cs[base + lane];
  float o1 = cs[base + lane + 64];
  float ss = o0 * o0 + o1 * o1;
#pragma unroll
  for (int m = 1; m < 64; m <<= 1) ss += __shfl_xor(ss, m, 64);
  float rms = rsqrtf(ss * (1.f / 128.f) + EPSf);
  float z0 = zbuf[zb + lane];
  float z1 = zbuf[zb + lane + 64];
  cs[base + lane]      = o0 * rms * norm_w[lane]      * (z0 / (1.f + expf(-z0)));
  cs[base + lane + 64] = o1 * rms * norm_w[lane + 64] * (z1 / (1.f + expf(-z1)));
}

extern "C" void kernel_launch(void* const* d_in, const int* in_sizes, int n_in,
                              void* d_out, int out_size, void* d_ws, size_t ws_size,
                              hipStream_t stream) {
  const float* hs        = (const float*)d_in[0];
  const float* conv_st   = (const float*)d_in[1];
  const float* rec_st    = (const float*)d_in[2];
  const int*   ctx       = (const int*)d_in[3];
  const float* W_qkv     = (const float*)d_in[4];
  const float* W_z       = (const float*)d_in[5];
  const float* W_b       = (const float*)d_in[6];
  const float* W_a       = (const float*)d_in[7];
  const float* conv_w    = (const float*)d_in[8];
  const float* conv_b    = (const float*)d_in[9];
  const float* A_log     = (const float*)d_in[10];
  const float* dt_bias   = (const float*)d_in[11];
  const float* norm_w    = (const float*)d_in[12];
  const float* W_out     = (const float*)d_in[13];

  float* out0   = (float*)d_out;                          // [B,S,H]
  float* out_cv = out0 + (size_t)MM * HH;                 // [B,CONVD,K-1]
  float* out_sf = out_cv + (size_t)BB * CONVD * (KC - 1); // [B,HV,DK,DV]

  float* mixed = (float*)d_ws;                        // MM*CONVD   (16 MB) raw
  float* cs    = mixed + (size_t)MM * CONVD;          // MM*CONVD   (16 MB) conv+silu / o
  float* zbuf  = cs + (size_t)MM * CONVD;             // MM*VALD    (8 MB)
  float* gbuf  = zbuf + (size_t)MM * VALD;            // MM*HV
  float* betab = gbuf + (size_t)MM * HVc;             // MM*HV

  // 1) mixed = hs @ W_qkv (MFMA bf16)
  gemm_mfma<<<dim3(CONVD / 128, MM / 64), 256, 0, stream>>>(hs, W_qkv, mixed, MM, CONVD, HH, HH);
  // 2) z = hs @ W_z
  gemm_mfma<<<dim3(VALD / 128, MM / 64), 256, 0, stream>>>(hs, W_z, zbuf, MM, VALD, HH, HH);
  // 3) b,a projections + gating
  proj_ab_kernel<<<MM, 256, 0, stream>>>(hs, W_b, W_a, A_log, dt_bias, gbuf, betab);
  // 4) conv + silu, parallel over s-chunks (mixed -> cs)
  conv_par_kernel<<<dim3(CONVD / 256, SEQ / CCH, BB), 256, 0, stream>>>(
      mixed, conv_st, conv_w, conv_b, cs);
  // 5) conv_state_out from raw mixed
  conv_state_out_kernel<<<(BB * CONVD * (KC - 1)) / 256, 256, 0, stream>>>(mixed, out_cv);
  // 6) l2norm q,k in place on cs
  l2norm_kernel<<<MM * HKc * 2, 64, 0, stream>>>(cs);
  // 7) delta-rule scan (o overwrites v slot of cs)
  scan_kernel<<<BB * HVc, 256, 0, stream>>>(cs, gbuf, betab, rec_st, ctx, out_sf);
  // 8) gated RMSNorm + silu(z) in place on cs
  normgate_kernel<<<MM * HVc, 64, 0, stream>>>(cs, zbuf, norm_w);
  // 9) output = o @ W_out (MFMA bf16), A strided with lda=CONVD
  gemm_mfma<<<dim3(HH / 128, MM / 64), 256, 0, stream>>>(
      cs + 2 * KEYD, W_out, out0, MM, HH, VALD, CONVD);
}

// Round 6
// 760.853 us; speedup vs baseline: 2.9230x; 1.2418x over previous
//
#include <hip/hip_runtime.h>
#include <hip/hip_bf16.h>

// Problem constants
#define BB     2
#define SEQ    256
#define HH     2048
#define HKc    16
#define HVc    32
#define DKc    128
#define DVc    128
#define KC     4
#define KEYD   2048      // HKc*DKc
#define VALD   4096      // HVc*DVc
#define CONVD  8192      // 2*KEYD + VALD
#define MM     (BB*SEQ)  // 512
#define EPSf   1e-6f

typedef __attribute__((ext_vector_type(8))) short short8;
typedef __attribute__((ext_vector_type(4))) short short4v;
typedef __attribute__((ext_vector_type(4))) float floatx4;

__device__ __forceinline__ short f2bf(float f) {
  union { float f; unsigned u; } v; v.f = f;
  unsigned r = v.u + 0x7fffu + ((v.u >> 16) & 1u);   // RNE
  return (short)(r >> 16);
}

// ---------- MFMA bf16 GEMM: C[M,N] = A[M,K](fp32,lda) * B[K,N](fp32) -------
// Block tile 64m x 128n, BK=32, 256 threads = 4 waves (2x2), wave = 32m x 64n.
#define PADs 40   // shorts per LDS row: 32 data + 8 pad (80 B, 16B-aligned)
__global__ __launch_bounds__(256) void gemm_mfma(
    const float* __restrict__ A, const float* __restrict__ Bw,
    float* __restrict__ C, int M, int N, int Kd, int lda) {
  __shared__ short As[64 * PADs];
  __shared__ short Bs[128 * PADs];
  const int tid = threadIdx.x;
  const int wave = tid >> 6, lane = tid & 63;
  const int wm = (wave >> 1) * 32, wn = (wave & 1) * 64;
  const int bm = blockIdx.y * 64, bn = blockIdx.x * 128;
  floatx4 acc[2][4] = {};
  // A staging: kq = float4-index (8 per row), rows m0, m0+32
  const int a_kq = tid & 7, a_m0 = tid >> 3;
  // B staging (transpose): n = tid&127, k-runs of 8
  const int b_n = tid & 127, b_kh = (tid >> 7) * 8;
  const int fm = lane & 15, fq = (lane >> 4) * 8;
  for (int k0 = 0; k0 < Kd; k0 += 32) {
#pragma unroll
    for (int r = 0; r < 2; ++r) {
      int m = a_m0 + r * 32;
      const float4 f = *(const float4*)(A + (size_t)(bm + m) * lda + k0 + a_kq * 4);
      short4v sv; sv[0] = f2bf(f.x); sv[1] = f2bf(f.y); sv[2] = f2bf(f.z); sv[3] = f2bf(f.w);
      *(short4v*)&As[m * PADs + a_kq * 4] = sv;
    }
#pragma unroll
    for (int r = 0; r < 2; ++r) {
      int kk = b_kh + r * 16;
      short8 s;
#pragma unroll
      for (int j = 0; j < 8; ++j)
        s[j] = f2bf(Bw[(size_t)(k0 + kk + j) * N + bn + b_n]);
      *(short8*)&Bs[b_n * PADs + kk] = s;
    }
    __syncthreads();
    short8 af[2], bfr[4];
#pragma unroll
    for (int i = 0; i < 2; ++i)
      af[i] = *(const short8*)&As[(wm + i * 16 + fm) * PADs + fq];
#pragma unroll
    for (int j = 0; j < 4; ++j)
      bfr[j] = *(const short8*)&Bs[(wn + j * 16 + fm) * PADs + fq];
#pragma unroll
    for (int i = 0; i < 2; ++i)
#pragma unroll
      for (int j = 0; j < 4; ++j)
        acc[i][j] = __builtin_amdgcn_mfma_f32_16x16x32_bf16(af[i], bfr[j], acc[i][j], 0, 0, 0);
    __syncthreads();
  }
  // C/D layout: col = lane&15, row = (lane>>4)*4 + reg
  const int cn = lane & 15, cr0 = (lane >> 4) * 4;
#pragma unroll
  for (int i = 0; i < 2; ++i)
#pragma unroll
    for (int j = 0; j < 4; ++j)
#pragma unroll
      for (int r = 0; r < 4; ++r)
        C[(size_t)(bm + wm + i * 16 + cr0 + r) * N + bn + wn + j * 16 + cn] = acc[i][j][r];
}

// -------- b/a projections fused with gating --------
__global__ __launch_bounds__(256) void proj_ab_kernel(
    const float* __restrict__ hs, const float* __restrict__ Wb,
    const float* __restrict__ Wa, const float* __restrict__ A_log,
    const float* __restrict__ dt_bias, float* __restrict__ g_out,
    float* __restrict__ beta_out) {
  __shared__ float xs[HH];
  __shared__ float part[4][64];
  const int row = blockIdx.x;
  const int t = threadIdx.x;
  for (int i = t; i < HH; i += 256) xs[i] = hs[(size_t)row * HH + i];
  __syncthreads();
  const int j = t & 63;
  const int kc = t >> 6;
  const float* W = (j < 32) ? Wb : Wa;
  const int jj = j & 31;
  float p = 0.f;
  const int k0 = kc * 512;
#pragma unroll 8
  for (int k = k0; k < k0 + 512; ++k) p += xs[k] * W[k * 32 + jj];
  part[kc][j] = p;
  __syncthreads();
  if (t < 64) {
    float dot = part[0][t] + part[1][t] + part[2][t] + part[3][t];
    if (t < 32) {
      beta_out[row * HVc + t] = 1.f / (1.f + expf(-dot));
    } else {
      int h = t - 32;
      float x = dot + dt_bias[h];
      float sp = (x > 20.f) ? x : log1pf(expf(x));
      g_out[row * HVc + h] = -expf(A_log[h]) * sp;
    }
  }
}

// -------- depthwise causal conv (K=4) + SiLU, parallel over s-chunks --------
#define CCH 16
__global__ __launch_bounds__(256) void conv_par_kernel(
    const float* __restrict__ mixed, const float* __restrict__ conv_state,
    const float* __restrict__ conv_w, const float* __restrict__ conv_b,
    float* __restrict__ cs) {
  const int c = blockIdx.x * 256 + threadIdx.x;   // channel
  const int s0 = blockIdx.y * CCH;
  const int b = blockIdx.z;
  const float4 w4 = *(const float4*)&conv_w[c * KC];
  const float bias = conv_b[c];
  float r0, r1, r2;
  if (s0 == 0) {
    size_t sb = (size_t)(b * CONVD + c) * (KC - 1);
    r0 = conv_state[sb + 0]; r1 = conv_state[sb + 1]; r2 = conv_state[sb + 2];
  } else {
    r0 = mixed[((size_t)(b * SEQ + s0 - 3)) * CONVD + c];
    r1 = mixed[((size_t)(b * SEQ + s0 - 2)) * CONVD + c];
    r2 = mixed[((size_t)(b * SEQ + s0 - 1)) * CONVD + c];
  }
#pragma unroll
  for (int s = s0; s < s0 + CCH; ++s) {
    size_t off = ((size_t)(b * SEQ + s)) * CONVD + c;
    float x = mixed[off];
    float acc = bias + r0 * w4.x + r1 * w4.y + r2 * w4.z + x * w4.w;
    cs[off] = acc / (1.f + expf(-acc));
    r0 = r1; r1 = r2; r2 = x;
  }
}

// -------- conv_state_out: last K-1 raw rows of mixed, [B,C,K-1] fp32 --------
__global__ __launch_bounds__(256) void conv_state_out_kernel(
    const float* __restrict__ mixed, float* __restrict__ out2) {
  int idx = blockIdx.x * 256 + threadIdx.x;  // over BB*CONVD*(KC-1)
  int t = idx % (KC - 1);
  int c = (idx / (KC - 1)) & (CONVD - 1);
  int b = idx / ((KC - 1) * CONVD);
  out2[idx] = mixed[((size_t)(b * SEQ + SEQ - (KC - 1) + t)) * CONVD + c];
}

// -------- per-head l2norm of q (scaled by DK^-0.5) and k, IN PLACE on cs ----
__global__ __launch_bounds__(64) void l2norm_kernel(float* __restrict__ cs) {
  int bx = blockIdx.x;          // row*32 + head*2 + which
  int which = bx & 1;
  int head = (bx >> 1) & 15;
  int row = bx >> 5;
  int lane = threadIdx.x;
  size_t base = (size_t)row * CONVD + (size_t)which * KEYD + head * DKc;
  float v0 = cs[base + lane];
  float v1 = cs[base + lane + 64];
  float ss = v0 * v0 + v1 * v1;
#pragma unroll
  for (int m = 1; m < 64; m <<= 1) ss += __shfl_xor(ss, m, 64);
  float rn = rsqrtf(ss + EPSf);
  if (!which) rn *= 0.08838834764831845f;  // DK^-0.5
  cs[base + lane] = v0 * rn;
  cs[base + lane + 64] = v1 * rn;
}

// -------- delta-rule scan: ONE WAVE per block, 256 blocks, zero barriers ----
// Block = (vg, h, b): 32 v-columns. lane = col(0..31) + 32*khf.
// Prefetch next step's k/q/v/g/beta into regs; LDS k/q broadcast double-buffered.
__global__ __launch_bounds__(64) void scan_kernel(
    float* __restrict__ cs, const float* __restrict__ g_in,
    const float* __restrict__ beta_in, const float* __restrict__ rs0,
    const int* __restrict__ ctx, float* __restrict__ sfin) {
  const int vg = blockIdx.x, h = blockIdx.y, b = blockIdx.z;
  const int bh = b * HVc + h;
  const int lane = threadIdx.x;
  const int col = (lane & 31) + vg * 32;
  const int khf = lane >> 5;
  const int khead = h >> 1;           // GQA rep=2
  __shared__ float ksh[2][128], qsh[2][128];
  float S[64];
#pragma unroll
  for (int i = 0; i < 64; ++i)
    S[i] = rs0[((size_t)bh * DKc + khf * 64 + i) * DVc + col];
  const int cl = ctx[b];
  const size_t kbase = KEYD + (size_t)khead * DKc;
  const size_t qbase = (size_t)khead * DKc;
  const size_t vcol  = 2 * KEYD + (size_t)h * DVc + col;
  // prefetch step 0
  size_t rb0 = (size_t)(b * SEQ) * CONVD;
  float kr0 = cs[rb0 + kbase + lane], kr1 = cs[rb0 + kbase + lane + 64];
  float qr0 = cs[rb0 + qbase + lane], qr1 = cs[rb0 + qbase + lane + 64];
  float vr  = cs[rb0 + vcol];
  float gr  = g_in[(b * SEQ) * HVc + h];
  float br  = beta_in[(b * SEQ) * HVc + h];
  for (int s = 0; s < SEQ; ++s) {
    const int buf = s & 1;
    ksh[buf][lane] = kr0; ksh[buf][lane + 64] = kr1;
    qsh[buf][lane] = qr0; qsh[buf][lane + 64] = qr1;
    // prefetch step s+1 (clamped)
    const int sn = (s + 1 < SEQ) ? s + 1 : s;
    const size_t rbn = (size_t)(b * SEQ + sn) * CONVD;
    float nk0 = cs[rbn + kbase + lane], nk1 = cs[rbn + kbase + lane + 64];
    float nq0 = cs[rbn + qbase + lane], nq1 = cs[rbn + qbase + lane + 64];
    float nv  = cs[rbn + vcol];
    float ngg = g_in[(b * SEQ + sn) * HVc + h];
    float nbb = beta_in[(b * SEQ + sn) * HVc + h];
    const size_t obase = (size_t)(b * SEQ + s) * CONVD + vcol;
    if (s < cl) {
      float eg = expf(gr);
      const float4* k4 = (const float4*)&ksh[buf][khf * 64];
      const float4* q4 = (const float4*)&qsh[buf][khf * 64];
      float kv0 = 0.f, kv1 = 0.f, kv2 = 0.f, kv3 = 0.f;
#pragma unroll
      for (int i = 0; i < 16; ++i) {
        float4 kk = k4[i];
        S[4*i+0] *= eg; kv0 += kk.x * S[4*i+0];
        S[4*i+1] *= eg; kv1 += kk.y * S[4*i+1];
        S[4*i+2] *= eg; kv2 += kk.z * S[4*i+2];
        S[4*i+3] *= eg; kv3 += kk.w * S[4*i+3];
      }
      float kvp = (kv0 + kv1) + (kv2 + kv3);
      float kv = kvp + __shfl_xor(kvp, 32, 64);
      float delta = (vr - kv) * br;
      float o0 = 0.f, o1 = 0.f, o2 = 0.f, o3 = 0.f;
#pragma unroll
      for (int i = 0; i < 16; ++i) {
        float4 kk = k4[i];
        float4 qq = q4[i];
        S[4*i+0] += kk.x * delta; o0 += qq.x * S[4*i+0];
        S[4*i+1] += kk.y * delta; o1 += qq.y * S[4*i+1];
        S[4*i+2] += kk.z * delta; o2 += qq.z * S[4*i+2];
        S[4*i+3] += kk.w * delta; o3 += qq.w * S[4*i+3];
      }
      float op = (o0 + o1) + (o2 + o3);
      float o = op + __shfl_xor(op, 32, 64);
      if (!khf) cs[obase] = o;          // coalesced 128B line (lanes 0-31)
    } else {
      if (!khf) cs[obase] = 0.f;
    }
    kr0 = nk0; kr1 = nk1; qr0 = nq0; qr1 = nq1; vr = nv; gr = ngg; br = nbb;
  }
#pragma unroll
  for (int i = 0; i < 64; ++i)
    sfin[((size_t)bh * DKc + khf * 64 + i) * DVc + col] = S[i];
}

// -------- gated RMSNorm over DV + SiLU(z), in place on o (v-slot of cs) -----
__global__ __launch_bounds__(64) void normgate_kernel(
    float* __restrict__ cs, const float* __restrict__ zbuf,
    const float* __restrict__ norm_w) {
  int bx = blockIdx.x;   // row*32 + h
  int h = bx & 31;
  int row = bx >> 5;
  int lane = threadIdx.x;
  size_t base = (size_t)row * CONVD + 2 * KEYD + h * DVc;
  size_t zb = (size_t)row * VALD + h * DVc;
  float o0 = cs[base + lane];
  float o1 = cs[base + lane + 64];
  float ss = o0 * o0 + o1 * o1;
#pragma unroll
  for (int m = 1; m < 64; m <<= 1) ss += __shfl_xor(ss, m, 64);
  float rms = rsqrtf(ss * (1.f / 128.f) + EPSf);
  float z0 = zbuf[zb + lane];
  float z1 = zbuf[zb + lane + 64];
  cs[base + lane]      = o0 * rms * norm_w[lane]      * (z0 / (1.f + expf(-z0)));
  cs[base + lane + 64] = o1 * rms * norm_w[lane + 64] * (z1 / (1.f + expf(-z1)));
}

extern "C" void kernel_launch(void* const* d_in, const int* in_sizes, int n_in,
                              void* d_out, int out_size, void* d_ws, size_t ws_size,
                              hipStream_t stream) {
  const float* hs        = (const float*)d_in[0];
  const float* conv_st   = (const float*)d_in[1];
  const float* rec_st    = (const float*)d_in[2];
  const int*   ctx       = (const int*)d_in[3];
  const float* W_qkv     = (const float*)d_in[4];
  const float* W_z       = (const float*)d_in[5];
  const float* W_b       = (const float*)d_in[6];
  const float* W_a       = (const float*)d_in[7];
  const float* conv_w    = (const float*)d_in[8];
  const float* conv_b    = (const float*)d_in[9];
  const float* A_log     = (const float*)d_in[10];
  const float* dt_bias   = (const float*)d_in[11];
  const float* norm_w    = (const float*)d_in[12];
  const float* W_out     = (const float*)d_in[13];

  float* out0   = (float*)d_out;                          // [B,S,H]
  float* out_cv = out0 + (size_t)MM * HH;                 // [B,CONVD,K-1]
  float* out_sf = out_cv + (size_t)BB * CONVD * (KC - 1); // [B,HV,DK,DV]

  float* mixed = (float*)d_ws;                        // MM*CONVD   (16 MB) raw
  float* cs    = mixed + (size_t)MM * CONVD;          // MM*CONVD   (16 MB) conv+silu / o
  float* zbuf  = cs + (size_t)MM * CONVD;             // MM*VALD    (8 MB)
  float* gbuf  = zbuf + (size_t)MM * VALD;            // MM*HV
  float* betab = gbuf + (size_t)MM * HVc;             // MM*HV

  // 1) mixed = hs @ W_qkv (MFMA bf16)
  gemm_mfma<<<dim3(CONVD / 128, MM / 64), 256, 0, stream>>>(hs, W_qkv, mixed, MM, CONVD, HH, HH);
  // 2) z = hs @ W_z
  gemm_mfma<<<dim3(VALD / 128, MM / 64), 256, 0, stream>>>(hs, W_z, zbuf, MM, VALD, HH, HH);
  // 3) b,a projections + gating
  proj_ab_kernel<<<MM, 256, 0, stream>>>(hs, W_b, W_a, A_log, dt_bias, gbuf, betab);
  // 4) conv + silu, parallel over s-chunks (mixed -> cs)
  conv_par_kernel<<<dim3(CONVD / 256, SEQ / CCH, BB), 256, 0, stream>>>(
      mixed, conv_st, conv_w, conv_b, cs);
  // 5) conv_state_out from raw mixed
  conv_state_out_kernel<<<(BB * CONVD * (KC - 1)) / 256, 256, 0, stream>>>(mixed, out_cv);
  // 6) l2norm q,k in place on cs
  l2norm_kernel<<<MM * HKc * 2, 64, 0, stream>>>(cs);
  // 7) delta-rule scan: 256 one-wave blocks (vg, h, b)
  scan_kernel<<<dim3(4, HVc, BB), 64, 0, stream>>>(cs, gbuf, betab, rec_st, ctx, out_sf);
  // 8) gated RMSNorm + silu(z) in place on cs
  normgate_kernel<<<MM * HVc, 64, 0, stream>>>(cs, zbuf, norm_w);
  // 9) output = o @ W_out (MFMA bf16), A strided with lda=CONVD
  gemm_mfma<<<dim3(HH / 128, MM / 64), 256, 0, stream>>>(
      cs + 2 * KEYD, W_out, out0, MM, HH, VALD, CONVD);
}

// Round 7
// 662.246 us; speedup vs baseline: 3.3582x; 1.1489x over previous
//
#include <hip/hip_runtime.h>
#include <hip/hip_bf16.h>

// Problem constants
#define BB     2
#define SEQ    256
#define HH     2048
#define HKc    16
#define HVc    32
#define DKc    128
#define DVc    128
#define KC     4
#define KEYD   2048      // HKc*DKc
#define VALD   4096      // HVc*DVc
#define CONVD  8192      // 2*KEYD + VALD
#define MM     (BB*SEQ)  // 512
#define EPSf   1e-6f

typedef __attribute__((ext_vector_type(8))) short short8;
typedef __attribute__((ext_vector_type(4))) short short4v;
typedef __attribute__((ext_vector_type(4))) float floatx4;

__device__ __forceinline__ short f2bf(float f) {
  union { float f; unsigned u; } v; v.f = f;
  unsigned r = v.u + 0x7fffu + ((v.u >> 16) & 1u);   // RNE
  return (short)(r >> 16);
}

// ---------- MFMA bf16 GEMM: C[M,N] = A[M,K](fp32,lda) * B[K,N](fp32) -------
// Block tile 64m x 128n, BK=32, 256 threads = 4 waves (2x2), wave = 32m x 64n.
#define PADs 40   // shorts per LDS row: 32 data + 8 pad (80 B, 16B-aligned)
__global__ __launch_bounds__(256) void gemm_mfma(
    const float* __restrict__ A, const float* __restrict__ Bw,
    float* __restrict__ C, int M, int N, int Kd, int lda) {
  __shared__ short As[64 * PADs];
  __shared__ short Bs[128 * PADs];
  const int tid = threadIdx.x;
  const int wave = tid >> 6, lane = tid & 63;
  const int wm = (wave >> 1) * 32, wn = (wave & 1) * 64;
  const int bm = blockIdx.y * 64, bn = blockIdx.x * 128;
  floatx4 acc[2][4] = {};
  const int a_kq = tid & 7, a_m0 = tid >> 3;
  const int b_n = tid & 127, b_kh = (tid >> 7) * 8;
  const int fm = lane & 15, fq = (lane >> 4) * 8;
  for (int k0 = 0; k0 < Kd; k0 += 32) {
#pragma unroll
    for (int r = 0; r < 2; ++r) {
      int m = a_m0 + r * 32;
      const float4 f = *(const float4*)(A + (size_t)(bm + m) * lda + k0 + a_kq * 4);
      short4v sv; sv[0] = f2bf(f.x); sv[1] = f2bf(f.y); sv[2] = f2bf(f.z); sv[3] = f2bf(f.w);
      *(short4v*)&As[m * PADs + a_kq * 4] = sv;
    }
#pragma unroll
    for (int r = 0; r < 2; ++r) {
      int kk = b_kh + r * 16;
      short8 s;
#pragma unroll
      for (int j = 0; j < 8; ++j)
        s[j] = f2bf(Bw[(size_t)(k0 + kk + j) * N + bn + b_n]);
      *(short8*)&Bs[b_n * PADs + kk] = s;
    }
    __syncthreads();
    short8 af[2], bfr[4];
#pragma unroll
    for (int i = 0; i < 2; ++i)
      af[i] = *(const short8*)&As[(wm + i * 16 + fm) * PADs + fq];
#pragma unroll
    for (int j = 0; j < 4; ++j)
      bfr[j] = *(const short8*)&Bs[(wn + j * 16 + fm) * PADs + fq];
#pragma unroll
    for (int i = 0; i < 2; ++i)
#pragma unroll
      for (int j = 0; j < 4; ++j)
        acc[i][j] = __builtin_amdgcn_mfma_f32_16x16x32_bf16(af[i], bfr[j], acc[i][j], 0, 0, 0);
    __syncthreads();
  }
  const int cn = lane & 15, cr0 = (lane >> 4) * 4;
#pragma unroll
  for (int i = 0; i < 2; ++i)
#pragma unroll
    for (int j = 0; j < 4; ++j)
#pragma unroll
      for (int r = 0; r < 4; ++r)
        C[(size_t)(bm + wm + i * 16 + cr0 + r) * N + bn + wn + j * 16 + cn] = acc[i][j][r];
}

// -------- b/a projections fused with gating --------
__global__ __launch_bounds__(256) void proj_ab_kernel(
    const float* __restrict__ hs, const float* __restrict__ Wb,
    const float* __restrict__ Wa, const float* __restrict__ A_log,
    const float* __restrict__ dt_bias, float* __restrict__ g_out,
    float* __restrict__ beta_out) {
  __shared__ float xs[HH];
  __shared__ float part[4][64];
  const int row = blockIdx.x;
  const int t = threadIdx.x;
  for (int i = t; i < HH; i += 256) xs[i] = hs[(size_t)row * HH + i];
  __syncthreads();
  const int j = t & 63;
  const int kc = t >> 6;
  const float* W = (j < 32) ? Wb : Wa;
  const int jj = j & 31;
  float p = 0.f;
  const int k0 = kc * 512;
#pragma unroll 8
  for (int k = k0; k < k0 + 512; ++k) p += xs[k] * W[k * 32 + jj];
  part[kc][j] = p;
  __syncthreads();
  if (t < 64) {
    float dot = part[0][t] + part[1][t] + part[2][t] + part[3][t];
    if (t < 32) {
      beta_out[row * HVc + t] = 1.f / (1.f + expf(-dot));
    } else {
      int h = t - 32;
      float x = dot + dt_bias[h];
      float sp = (x > 20.f) ? x : log1pf(expf(x));
      g_out[row * HVc + h] = -expf(A_log[h]) * sp;
    }
  }
}

// -------- depthwise causal conv (K=4) + SiLU, parallel over s-chunks --------
#define CCH 16
__global__ __launch_bounds__(256) void conv_par_kernel(
    const float* __restrict__ mixed, const float* __restrict__ conv_state,
    const float* __restrict__ conv_w, const float* __restrict__ conv_b,
    float* __restrict__ cs) {
  const int c = blockIdx.x * 256 + threadIdx.x;   // channel
  const int s0 = blockIdx.y * CCH;
  const int b = blockIdx.z;
  const float4 w4 = *(const float4*)&conv_w[c * KC];
  const float bias = conv_b[c];
  float r0, r1, r2;
  if (s0 == 0) {
    size_t sb = (size_t)(b * CONVD + c) * (KC - 1);
    r0 = conv_state[sb + 0]; r1 = conv_state[sb + 1]; r2 = conv_state[sb + 2];
  } else {
    r0 = mixed[((size_t)(b * SEQ + s0 - 3)) * CONVD + c];
    r1 = mixed[((size_t)(b * SEQ + s0 - 2)) * CONVD + c];
    r2 = mixed[((size_t)(b * SEQ + s0 - 1)) * CONVD + c];
  }
#pragma unroll
  for (int s = s0; s < s0 + CCH; ++s) {
    size_t off = ((size_t)(b * SEQ + s)) * CONVD + c;
    float x = mixed[off];
    float acc = bias + r0 * w4.x + r1 * w4.y + r2 * w4.z + x * w4.w;
    cs[off] = acc / (1.f + expf(-acc));
    r0 = r1; r1 = r2; r2 = x;
  }
}

// -------- conv_state_out: last K-1 raw rows of mixed, [B,C,K-1] fp32 --------
__global__ __launch_bounds__(256) void conv_state_out_kernel(
    const float* __restrict__ mixed, float* __restrict__ out2) {
  int idx = blockIdx.x * 256 + threadIdx.x;  // over BB*CONVD*(KC-1)
  int t = idx % (KC - 1);
  int c = (idx / (KC - 1)) & (CONVD - 1);
  int b = idx / ((KC - 1) * CONVD);
  out2[idx] = mixed[((size_t)(b * SEQ + SEQ - (KC - 1) + t)) * CONVD + c];
}

// -------- per-head l2norm of q (scaled by DK^-0.5) and k, IN PLACE on cs ----
__global__ __launch_bounds__(64) void l2norm_kernel(float* __restrict__ cs) {
  int bx = blockIdx.x;          // row*32 + head*2 + which
  int which = bx & 1;
  int head = (bx >> 1) & 15;
  int row = bx >> 5;
  int lane = threadIdx.x;
  size_t base = (size_t)row * CONVD + (size_t)which * KEYD + head * DKc;
  float v0 = cs[base + lane];
  float v1 = cs[base + lane + 64];
  float ss = v0 * v0 + v1 * v1;
#pragma unroll
  for (int m = 1; m < 64; m <<= 1) ss += __shfl_xor(ss, m, 64);
  float rn = rsqrtf(ss + EPSf);
  if (!which) rn *= 0.08838834764831845f;  // DK^-0.5
  cs[base + lane] = v0 * rn;
  cs[base + lane + 64] = v1 * rn;
}

// -------- delta-rule scan v3: one wave/block, 512 blocks, chunked LDS -------
// Block = (vg 0..7, h, b): 16 v-cols. lane = c16(0..15) + 16*kq(0..3).
// S[32] = state[kq*32 .. +32)[col]. Chunks of SCH=16 steps double-buffered in
// LDS; chunk c+1 prefetched into registers while computing chunk c; exp(g)
// precomputed at staging. Zero barriers (single wave).
#define SCH 16
__global__ __launch_bounds__(64) void scan_kernel(
    float* __restrict__ cs, const float* __restrict__ g_in,
    const float* __restrict__ beta_in, const float* __restrict__ rs0,
    const int* __restrict__ ctx, float* __restrict__ sfin) {
  const int vg = blockIdx.x, h = blockIdx.y, b = blockIdx.z;
  const int bh = b * HVc + h;
  const int lane = threadIdx.x;
  const int kq = lane >> 4;         // k-quarter
  const int c16 = lane & 15;
  const int col = vg * 16 + c16;
  const int khead = h >> 1;         // GQA rep=2
  __shared__ float kl[2][SCH * 128];
  __shared__ float ql[2][SCH * 128];
  __shared__ float vl[2][SCH * 16];
  __shared__ float egl[2][SCH];
  __shared__ float btl[2][SCH];
  float S[32];
#pragma unroll
  for (int i = 0; i < 32; ++i)
    S[i] = rs0[((size_t)bh * DKc + kq * 32 + i) * DVc + col];
  const int cl = ctx[b];
  const size_t qg = (size_t)khead * DKc;
  const size_t kg = KEYD + (size_t)khead * DKc;
  const size_t vG = 2 * KEYD + (size_t)h * DVc + vg * 16;
  const int r0g = b * SEQ;
  const int sv = lane >> 2, cv = lane & 3;   // v staging: step, col-quad
  float4 kreg[8], qreg[8], vreg;
  float egr = 0.f, btr = 0.f;
  // ---- prologue: load + commit chunk 0
#pragma unroll
  for (int it = 0; it < 8; ++it) {
    int idx = it * 64 + lane, s = idx >> 5, d4 = idx & 31;
    const float* rp = cs + (size_t)(r0g + s) * CONVD;
    kreg[it] = *(const float4*)(rp + kg + d4 * 4);
    qreg[it] = *(const float4*)(rp + qg + d4 * 4);
  }
  vreg = *(const float4*)(cs + (size_t)(r0g + sv) * CONVD + vG + cv * 4);
  if (lane < SCH) egr = expf(g_in[(r0g + lane) * HVc + h]);
  else if (lane < 2 * SCH) btr = beta_in[(r0g + lane - SCH) * HVc + h];
#pragma unroll
  for (int it = 0; it < 8; ++it) {
    int idx = it * 64 + lane, s = idx >> 5, d4 = idx & 31;
    *(float4*)&kl[0][s * 128 + d4 * 4] = kreg[it];
    *(float4*)&ql[0][s * 128 + d4 * 4] = qreg[it];
  }
  *(float4*)&vl[0][sv * 16 + cv * 4] = vreg;
  if (lane < SCH) egl[0][lane] = egr;
  else if (lane < 2 * SCH) btl[0][lane - SCH] = btr;

  const int NCH = SEQ / SCH;
  for (int c = 0; c < NCH; ++c) {
    const int buf = c & 1;
    // prefetch chunk c+1 into registers (hidden behind this chunk's compute)
    if (c + 1 < NCH) {
      const int r1 = r0g + (c + 1) * SCH;
#pragma unroll
      for (int it = 0; it < 8; ++it) {
        int idx = it * 64 + lane, s = idx >> 5, d4 = idx & 31;
        const float* rp = cs + (size_t)(r1 + s) * CONVD;
        kreg[it] = *(const float4*)(rp + kg + d4 * 4);
        qreg[it] = *(const float4*)(rp + qg + d4 * 4);
      }
      vreg = *(const float4*)(cs + (size_t)(r1 + sv) * CONVD + vG + cv * 4);
      if (lane < SCH) egr = expf(g_in[(r1 + lane) * HVc + h]);
      else if (lane < 2 * SCH) btr = beta_in[(r1 + lane - SCH) * HVc + h];
    }
    // compute SCH steps from LDS
    for (int s = 0; s < SCH; ++s) {
      const int sg = c * SCH + s;
      const float eg = egl[buf][s], bt = btl[buf][s];
      const float vv = vl[buf][s * 16 + c16];
      const float4* k4 = (const float4*)&kl[buf][s * 128 + kq * 32];
      const float4* q4 = (const float4*)&ql[buf][s * 128 + kq * 32];
      const size_t ob = (size_t)(r0g + sg) * CONVD + vG + c16;
      if (sg < cl) {
        float a0 = 0.f, a1 = 0.f, a2 = 0.f, a3 = 0.f;
#pragma unroll
        for (int j = 0; j < 8; ++j) {
          float4 kk = k4[j];
          S[4*j+0] *= eg; a0 += kk.x * S[4*j+0];
          S[4*j+1] *= eg; a1 += kk.y * S[4*j+1];
          S[4*j+2] *= eg; a2 += kk.z * S[4*j+2];
          S[4*j+3] *= eg; a3 += kk.w * S[4*j+3];
        }
        float p = (a0 + a1) + (a2 + a3);
        p += __shfl_xor(p, 16, 64);
        p += __shfl_xor(p, 32, 64);
        const float delta = (vv - p) * bt;
        float o0 = 0.f, o1 = 0.f, o2 = 0.f, o3 = 0.f;
#pragma unroll
        for (int j = 0; j < 8; ++j) {
          float4 kk = k4[j], qq = q4[j];
          S[4*j+0] += kk.x * delta; o0 += qq.x * S[4*j+0];
          S[4*j+1] += kk.y * delta; o1 += qq.y * S[4*j+1];
          S[4*j+2] += kk.z * delta; o2 += qq.z * S[4*j+2];
          S[4*j+3] += kk.w * delta; o3 += qq.w * S[4*j+3];
        }
        float o = (o0 + o1) + (o2 + o3);
        o += __shfl_xor(o, 16, 64);
        o += __shfl_xor(o, 32, 64);
        if (kq == 0) cs[ob] = o;
      } else {
        if (kq == 0) cs[ob] = 0.f;
      }
    }
    // commit prefetched chunk to the other LDS buffer
    if (c + 1 < NCH) {
      const int nb = buf ^ 1;
#pragma unroll
      for (int it = 0; it < 8; ++it) {
        int idx = it * 64 + lane, s = idx >> 5, d4 = idx & 31;
        *(float4*)&kl[nb][s * 128 + d4 * 4] = kreg[it];
        *(float4*)&ql[nb][s * 128 + d4 * 4] = qreg[it];
      }
      *(float4*)&vl[nb][sv * 16 + cv * 4] = vreg;
      if (lane < SCH) egl[nb][lane] = egr;
      else if (lane < 2 * SCH) btl[nb][lane - SCH] = btr;
    }
  }
#pragma unroll
  for (int i = 0; i < 32; ++i)
    sfin[((size_t)bh * DKc + kq * 32 + i) * DVc + col] = S[i];
}

// -------- gated RMSNorm over DV + SiLU(z), in place on o (v-slot of cs) -----
__global__ __launch_bounds__(64) void normgate_kernel(
    float* __restrict__ cs, const float* __restrict__ zbuf,
    const float* __restrict__ norm_w) {
  int bx = blockIdx.x;   // row*32 + h
  int h = bx & 31;
  int row = bx >> 5;
  int lane = threadIdx.x;
  size_t base = (size_t)row * CONVD + 2 * KEYD + h * DVc;
  size_t zb = (size_t)row * VALD + h * DVc;
  float o0 = cs[base + lane];
  float o1 = cs[base + lane + 64];
  float ss = o0 * o0 + o1 * o1;
#pragma unroll
  for (int m = 1; m < 64; m <<= 1) ss += __shfl_xor(ss, m, 64);
  float rms = rsqrtf(ss * (1.f / 128.f) + EPSf);
  float z0 = zbuf[zb + lane];
  float z1 = zbuf[zb + lane + 64];
  cs[base + lane]      = o0 * rms * norm_w[lane]      * (z0 / (1.f + expf(-z0)));
  cs[base + lane + 64] = o1 * rms * norm_w[lane + 64] * (z1 / (1.f + expf(-z1)));
}

extern "C" void kernel_launch(void* const* d_in, const int* in_sizes, int n_in,
                              void* d_out, int out_size, void* d_ws, size_t ws_size,
                              hipStream_t stream) {
  const float* hs        = (const float*)d_in[0];
  const float* conv_st   = (const float*)d_in[1];
  const float* rec_st    = (const float*)d_in[2];
  const int*   ctx       = (const int*)d_in[3];
  const float* W_qkv     = (const float*)d_in[4];
  const float* W_z       = (const float*)d_in[5];
  const float* W_b       = (const float*)d_in[6];
  const float* W_a       = (const float*)d_in[7];
  const float* conv_w    = (const float*)d_in[8];
  const float* conv_b    = (const float*)d_in[9];
  const float* A_log     = (const float*)d_in[10];
  const float* dt_bias   = (const float*)d_in[11];
  const float* norm_w    = (const float*)d_in[12];
  const float* W_out     = (const float*)d_in[13];

  float* out0   = (float*)d_out;                          // [B,S,H]
  float* out_cv = out0 + (size_t)MM * HH;                 // [B,CONVD,K-1]
  float* out_sf = out_cv + (size_t)BB * CONVD * (KC - 1); // [B,HV,DK,DV]

  float* mixed = (float*)d_ws;                        // MM*CONVD   (16 MB) raw
  float* cs    = mixed + (size_t)MM * CONVD;          // MM*CONVD   (16 MB)
  float* zbuf  = cs + (size_t)MM * CONVD;             // MM*VALD    (8 MB)
  float* gbuf  = zbuf + (size_t)MM * VALD;            // MM*HV
  float* betab = gbuf + (size_t)MM * HVc;             // MM*HV

  // 1) mixed = hs @ W_qkv (MFMA bf16)
  gemm_mfma<<<dim3(CONVD / 128, MM / 64), 256, 0, stream>>>(hs, W_qkv, mixed, MM, CONVD, HH, HH);
  // 2) z = hs @ W_z
  gemm_mfma<<<dim3(VALD / 128, MM / 64), 256, 0, stream>>>(hs, W_z, zbuf, MM, VALD, HH, HH);
  // 3) b,a projections + gating
  proj_ab_kernel<<<MM, 256, 0, stream>>>(hs, W_b, W_a, A_log, dt_bias, gbuf, betab);
  // 4) conv + silu, parallel over s-chunks (mixed -> cs)
  conv_par_kernel<<<dim3(CONVD / 256, SEQ / CCH, BB), 256, 0, stream>>>(
      mixed, conv_st, conv_w, conv_b, cs);
  // 5) conv_state_out from raw mixed
  conv_state_out_kernel<<<(BB * CONVD * (KC - 1)) / 256, 256, 0, stream>>>(mixed, out_cv);
  // 6) l2norm q,k in place on cs
  l2norm_kernel<<<MM * HKc * 2, 64, 0, stream>>>(cs);
  // 7) delta-rule scan v3: 512 one-wave blocks (vg, h, b), chunked LDS
  scan_kernel<<<dim3(8, HVc, BB), 64, 0, stream>>>(cs, gbuf, betab, rec_st, ctx, out_sf);
  // 8) gated RMSNorm + silu(z) in place on cs
  normgate_kernel<<<MM * HVc, 64, 0, stream>>>(cs, zbuf, norm_w);
  // 9) output = o @ W_out (MFMA bf16), A strided with lda=CONVD
  gemm_mfma<<<dim3(HH / 128, MM / 64), 256, 0, stream>>>(
      cs + 2 * KEYD, W_out, out0, MM, HH, VALD, CONVD);
}